// Round 4
// baseline (357.801 us; speedup 1.0000x reference)
//
#include <hip/hip_runtime.h>
#include <math.h>

#define BQ 65536
#define NC 512
#define DD 512
#define BM 128
#define BN 256
#define BK 32
#define MARGIN 3e-3f
#define FINF 3.402823466e38f

typedef short bf16x8 __attribute__((ext_vector_type(8)));
typedef float f32x4 __attribute__((ext_vector_type(4)));

// ---- async global->LDS (16B per lane, linear LDS dest) -------------------
__device__ __forceinline__ void load_lds16(const float* g, unsigned int* l) {
    __builtin_amdgcn_global_load_lds(
        (const __attribute__((address_space(1))) unsigned int*)(const void*)g,
        (__attribute__((address_space(3))) unsigned int*)(void*)l, 16, 0, 0);
}

__device__ __forceinline__ unsigned int cvt_pk_bf16(float a, float b) {
    unsigned int r;
    asm("v_cvt_pk_bf16_f32 %0, %1, %2" : "=v"(r) : "v"(a), "v"(b));
    return r;  // low16 = bf16(a) RNE, high16 = bf16(b)
}

// 8 fp32 -> bf16 hi (RNE) + bf16 lo (RNE of residual). Same values as the
// round-3 split -> identical error budget, MARGIN unchanged.
__device__ __forceinline__ void cvt8(float4 f0, float4 f1,
                                     bf16x8* hi, bf16x8* lo) {
    unsigned int h01 = cvt_pk_bf16(f0.x, f0.y);
    unsigned int h23 = cvt_pk_bf16(f0.z, f0.w);
    unsigned int h45 = cvt_pk_bf16(f1.x, f1.y);
    unsigned int h67 = cvt_pk_bf16(f1.z, f1.w);
    float a0 = __uint_as_float(h01 << 16), a1 = __uint_as_float(h01 & 0xFFFF0000u);
    float a2 = __uint_as_float(h23 << 16), a3 = __uint_as_float(h23 & 0xFFFF0000u);
    float a4 = __uint_as_float(h45 << 16), a5 = __uint_as_float(h45 & 0xFFFF0000u);
    float a6 = __uint_as_float(h67 << 16), a7 = __uint_as_float(h67 & 0xFFFF0000u);
    union { bf16x8 v; unsigned int u[4]; } H, L;
    H.u[0] = h01; H.u[1] = h23; H.u[2] = h45; H.u[3] = h67;
    L.u[0] = cvt_pk_bf16(f0.x - a0, f0.y - a1);
    L.u[1] = cvt_pk_bf16(f0.z - a2, f0.w - a3);
    L.u[2] = cvt_pk_bf16(f1.x - a4, f1.y - a5);
    L.u[3] = cvt_pk_bf16(f1.z - a6, f1.w - a7);
    *hi = H.v; *lo = L.v;
}

__device__ __forceinline__ float pw128_sq(const float* __restrict__ p) {
    float r[8];
    #pragma unroll
    for (int j = 0; j < 8; ++j) r[j] = 0.0f;
    #pragma unroll
    for (int q = 0; q < 32; ++q) {
        float4 v = *(const float4*)(p + q * 4);
        const int e = (q & 1) << 2;
        r[e + 0] = __fadd_rn(r[e + 0], __fmul_rn(v.x, v.x));
        r[e + 1] = __fadd_rn(r[e + 1], __fmul_rn(v.y, v.y));
        r[e + 2] = __fadd_rn(r[e + 2], __fmul_rn(v.z, v.z));
        r[e + 3] = __fadd_rn(r[e + 3], __fmul_rn(v.w, v.w));
    }
    return __fadd_rn(__fadd_rn(__fadd_rn(r[0], r[1]), __fadd_rn(r[2], r[3])),
                     __fadd_rn(__fadd_rn(r[4], r[5]), __fadd_rn(r[6], r[7])));
}

// Pass 1: fp32 tiles DMA'd to LDS (global_load_lds, XOR-swizzled source),
// bf16 hi/lo split at frag-read time, bf16x3 MFMA, metric m = csq - 2 z.c,
// best+second-best tracking, marginal rows -> fp64 fixup worklist.
// LDS image per row: logical 16B-unit u stored at slot u^(R&7) -> b128 frag
// reads are <=2-way bank aliased (free), no pad needed (DMA dest is linear).
__global__ __launch_bounds__(256) void codebook_kernel(
    const float* __restrict__ Z, const float* __restrict__ Cb,
    float* __restrict__ out, int* __restrict__ wslist, int cap) {

    __shared__ __align__(16) unsigned int stage[12288];  // A[128][32dw] | B[256][32dw] @4096
    __shared__ float csq[NC];
    __shared__ int bif[BM];

    const int tid = threadIdx.x;
    const int m0 = blockIdx.x * BM;
    const int l = tid & 63, wid = tid >> 6;
    const int wr0 = (wid >> 1) * 64;     // wave row base
    const int wc0 = (wid & 1) * 128;     // wave col base within chunk
    const int g = l >> 4, c = l & 15;

    // csq for all 512 codes (also warms L2 with the codebook)
    #pragma unroll
    for (int cc = 0; cc < 2; ++cc) {
        const int code = tid + cc * 256;
        const float* p = Cb + (size_t)code * DD;
        float b0 = pw128_sq(p), b1 = pw128_sq(p + 128);
        float b2 = pw128_sq(p + 256), b3 = pw128_sq(p + 384);
        csq[code] = __fadd_rn(__fadd_rn(b0, b1), __fadd_rn(b2, b3));
    }

    float rb1 = FINF, rb2 = FINF; int ri1 = 0;   // running best (tid<128)
    f32x4 acc[4][8];

    for (int step = 0; step < 32; ++step) {
        const int kt = (step & 15) * BK;
        const int n0 = (step >> 4) * BN;
        if ((step & 15) == 0) {
            #pragma unroll
            for (int i = 0; i < 4; ++i)
                #pragma unroll
                for (int j = 0; j < 8; ++j) acc[i][j] = (f32x4)0.0f;
        }
        __syncthreads();   // all frag reads of prev step done -> LDS reusable
        // DMA this step's tiles (A first: longer-latency HBM stream)
        #pragma unroll
        for (int i = 0; i < 4; ++i) {
            int n = tid + i * 256;
            int R = n >> 3, u = (n & 7) ^ (R & 7);
            load_lds16(Z + (size_t)(m0 + R) * DD + kt + u * 4, &stage[n * 4]);
        }
        #pragma unroll
        for (int i = 0; i < 8; ++i) {
            int n = tid + i * 256;
            int C = n >> 3, u = (n & 7) ^ (C & 7);
            load_lds16(Cb + (size_t)(n0 + C) * DD + kt + u * 4, &stage[4096 + n * 4]);
        }
        __syncthreads();   // compiler drains vmcnt before s_barrier

        // A fragments: fp32 read + in-register bf16 hi/lo split
        bf16x8 ah[4], al[4];
        #pragma unroll
        for (int i = 0; i < 4; ++i) {
            int R = wr0 + i * 16 + c;
            const unsigned int* ar = &stage[R * 32];
            float4 f0 = *(const float4*)&ar[((2 * g) ^ (R & 7)) * 4];
            float4 f1 = *(const float4*)&ar[((2 * g + 1) ^ (R & 7)) * 4];
            cvt8(f0, f1, &ah[i], &al[i]);
        }
        // B fragments per j + 96 MFMA (hi*hi + hi*lo + lo*hi)
        #pragma unroll
        for (int j = 0; j < 8; ++j) {
            int C = wc0 + j * 16 + c;
            const unsigned int* br = &stage[4096 + C * 32];
            float4 f0 = *(const float4*)&br[((2 * g) ^ (C & 7)) * 4];
            float4 f1 = *(const float4*)&br[((2 * g + 1) ^ (C & 7)) * 4];
            bf16x8 bh, bl;
            cvt8(f0, f1, &bh, &bl);
            #pragma unroll
            for (int i = 0; i < 4; ++i) {
                acc[i][j] = __builtin_amdgcn_mfma_f32_16x16x32_bf16(ah[i], bh, acc[i][j], 0, 0, 0);
                acc[i][j] = __builtin_amdgcn_mfma_f32_16x16x32_bf16(ah[i], bl, acc[i][j], 0, 0, 0);
                acc[i][j] = __builtin_amdgcn_mfma_f32_16x16x32_bf16(al[i], bh, acc[i][j], 0, 0, 0);
            }
        }

        if ((step & 15) == 15) {
            // chunk epilogue; red arrays alias the stage buffer
            __syncthreads();   // all waves done reading frags this step
            float* red_b1 = (float*)stage;            // [2][BM]
            int*   red_i1 = (int*)(stage + 256);      // [2][BM]
            float* red_b2 = (float*)(stage + 512);    // [2][BM]
            #pragma unroll
            for (int i = 0; i < 4; ++i) {
                #pragma unroll
                for (int r = 0; r < 4; ++r) {
                    float b1 = FINF, b2 = FINF; int i1 = 0;
                    #pragma unroll
                    for (int j = 0; j < 8; ++j) {
                        int code = n0 + wc0 + j * 16 + c;
                        float m = fmaf(-2.0f, acc[i][j][r], csq[code]);
                        if (m < b1) { b2 = b1; b1 = m; i1 = code; }
                        else b2 = fminf(b2, m);
                    }
                    #pragma unroll
                    for (int s = 1; s < 16; s <<= 1) {
                        float ob1 = __shfl_xor(b1, s);
                        float ob2 = __shfl_xor(b2, s);
                        int oi1 = __shfl_xor(i1, s);
                        if (ob1 < b1 || (ob1 == b1 && oi1 < i1)) {
                            b2 = fminf(b1, ob2); b1 = ob1; i1 = oi1;
                        } else {
                            b2 = fminf(b2, ob1);
                        }
                    }
                    if (c == 0) {
                        int row = wr0 + i * 16 + g * 4 + r;
                        red_b1[(wid & 1) * BM + row] = b1;
                        red_b2[(wid & 1) * BM + row] = b2;
                        red_i1[(wid & 1) * BM + row] = i1;
                    }
                }
            }
            __syncthreads();
            if (tid < BM) {
                #pragma unroll
                for (int h = 0; h < 2; ++h) {   // ascending code order
                    float nb1 = red_b1[h * BM + tid], nb2 = red_b2[h * BM + tid];
                    int ni = red_i1[h * BM + tid];
                    if (nb1 < rb1) { rb2 = fminf(rb1, nb2); rb1 = nb1; ri1 = ni; }
                    else rb2 = fminf(rb2, nb1);
                }
            }
            // loop-top __syncthreads protects stage reuse vs this merge
        }
    }

    if (tid < BM) {
        bif[tid] = ri1;
        out[(size_t)BQ * NC + m0 + tid] = (float)ri1;
        if (rb2 - rb1 < MARGIN) {
            int slot = atomicAdd(wslist, 1);
            if (slot < cap) wslist[1 + slot] = m0 + tid;
        }
    }
    __syncthreads();

    // one_hot: 128 rows x 512 cols, coalesced float4 stores
    #pragma unroll 4
    for (int t = 0; t < 64; ++t) {
        int f4i = tid + t * 256;
        int r = f4i >> 7, c4 = f4i & 127;
        int tgt = bif[r];
        int base = c4 * 4;
        float4 v;
        v.x = (tgt == base + 0) ? 1.0f : 0.0f;
        v.y = (tgt == base + 1) ? 1.0f : 0.0f;
        v.z = (tgt == base + 2) ? 1.0f : 0.0f;
        v.w = (tgt == base + 3) ? 1.0f : 0.0f;
        *(float4*)(out + (size_t)(m0 + r) * NC + (size_t)base) = v;
    }
}

// Pass 2: fp64-exact argmin for marginal rows (matches numpy-fp64 argmin).
__global__ __launch_bounds__(256) void fixup_kernel(
    const float* __restrict__ Z, const float* __restrict__ Cb,
    float* __restrict__ out, const int* __restrict__ wslist, int cap) {

    __shared__ float zrow[DD];
    __shared__ double md[256];
    __shared__ int mi[256];
    const int tid = threadIdx.x;
    int count = wslist[0];
    if (count > cap) count = cap;

    for (int e = blockIdx.x; e < count; e += gridDim.x) {
        const int row = wslist[1 + e];
        zrow[tid] = Z[(size_t)row * DD + tid];
        zrow[tid + 256] = Z[(size_t)row * DD + 256 + tid];
        __syncthreads();

        double bb = 1e300; int bidx = 0;
        #pragma unroll
        for (int cc = 0; cc < 2; ++cc) {
            const int code = tid * 2 + cc;
            const float* cp = Cb + (size_t)code * DD;
            double dot = 0.0, cs = 0.0;
            for (int k = 0; k < DD; k += 4) {
                float4 c4 = *(const float4*)(cp + k);
                double a0 = (double)zrow[k + 0], c0 = (double)c4.x;
                double a1 = (double)zrow[k + 1], c1 = (double)c4.y;
                double a2 = (double)zrow[k + 2], c2 = (double)c4.z;
                double a3 = (double)zrow[k + 3], c3 = (double)c4.w;
                dot = fma(a0, c0, dot); cs = fma(c0, c0, cs);
                dot = fma(a1, c1, dot); cs = fma(c1, c1, cs);
                dot = fma(a2, c2, dot); cs = fma(c2, c2, cs);
                dot = fma(a3, c3, dot); cs = fma(c3, c3, cs);
            }
            double m = cs - 2.0 * dot;
            if (m < bb || (m == bb && code < bidx)) { bb = m; bidx = code; }
        }
        md[tid] = bb; mi[tid] = bidx;
        __syncthreads();
        for (int s = 128; s > 0; s >>= 1) {
            if (tid < s) {
                if (md[tid + s] < md[tid] ||
                    (md[tid + s] == md[tid] && mi[tid + s] < mi[tid])) {
                    md[tid] = md[tid + s]; mi[tid] = mi[tid + s];
                }
            }
            __syncthreads();
        }
        const int imin = mi[0];
        out[(size_t)row * NC + tid] = (tid == imin) ? 1.0f : 0.0f;
        out[(size_t)row * NC + 256 + tid] = (tid + 256 == imin) ? 1.0f : 0.0f;
        if (tid == 0) out[(size_t)BQ * NC + row] = (float)imin;
        __syncthreads();
    }
}

extern "C" void kernel_launch(void* const* d_in, const int* in_sizes, int n_in,
                              void* d_out, int out_size, void* d_ws, size_t ws_size,
                              hipStream_t stream) {
    const float* Z = (const float*)d_in[0];
    const float* Cb = (const float*)d_in[1];
    float* out = (float*)d_out;
    int* wslist = (int*)d_ws;
    int cap = (int)(ws_size / 4) - 1;
    if (cap > BQ) cap = BQ;
    hipMemsetAsync(d_ws, 0, 4, stream);
    codebook_kernel<<<dim3(BQ / BM), dim3(256), 0, stream>>>(Z, Cb, out, wslist, cap);
    fixup_kernel<<<dim3(512), dim3(256), 0, stream>>>(Z, Cb, out, wslist, cap);
}